// Round 19
// baseline (277.365 us; speedup 1.0000x reference)
//
#include <hip/hip_runtime.h>
#include <hip/hip_bf16.h>

#define H 1024
#define SEQ 4096
#define BQ 64   // Kq
#define NB 16   // batch

typedef float f32x4 __attribute__((ext_vector_type(4)));
typedef __bf16 bf16x8 __attribute__((ext_vector_type(8)));

__device__ __forceinline__ void split_bf16(const float* x, bf16x8& hi, bf16x8& lo)
{
    #pragma unroll
    for (int i = 0; i < 8; ++i) {
        float v = x[i];
        __bf16 h = (__bf16)v;
        hi[i] = h;
        lo[i] = (__bf16)(v - (float)h);
    }
}

__device__ __forceinline__ void gload_lds16(const void* g, void* lds)
{
    __builtin_amdgcn_global_load_lds(
        (const __attribute__((address_space(1))) void*)g,
        (__attribute__((address_space(3))) void*)lds, 16, 0, 0);
}

// ---------------------------------------------------------------------------
// 512-thread split-K(x2)-in-block MFMA GEMM (BNK-true): C = A @ B^T*scale+bias
// CVEC: additionally cvec[m] += cscale * sum_n C[m][n]*bk[n] (atomic).
// ---------------------------------------------------------------------------
template<bool CVEC>
__global__ __launch_bounds__(512)
void gemm_bt_512(const float* __restrict__ A, const float* __restrict__ Bm,
                 const float* __restrict__ bias, float* __restrict__ C,
                 float scale, const float* __restrict__ bk,
                 float* __restrict__ cvec, float cscale)
{
    const int m0 = blockIdx.x * 64;
    const int n0 = blockIdx.y * 64;
    const int t   = threadIdx.x;
    const int w   = t >> 6;
    const int wm  = w & 3;      // m-subtile
    const int kh  = w >> 2;     // k-half
    const int l   = t & 63;
    const int row = l & 15;
    const int kg  = l >> 4;

    const float* ap = A + (size_t)(m0 + wm * 16 + row) * H + kh * 512 + kg * 8;
    const float* bp = Bm + (size_t)(n0 + row) * H + kh * 512 + kg * 8;

    f32x4 acc[4] = {};
    for (int k0 = 0; k0 < 512; k0 += 32) {
        float a8[8];
        *reinterpret_cast<float4*>(&a8[0]) = *reinterpret_cast<const float4*>(ap + k0);
        *reinterpret_cast<float4*>(&a8[4]) = *reinterpret_cast<const float4*>(ap + k0 + 4);
        bf16x8 ahi, alo;
        split_bf16(a8, ahi, alo);
        #pragma unroll
        for (int j = 0; j < 4; ++j) {
            float b8[8];
            const float* bjp = bp + (size_t)j * 16 * H + k0;
            *reinterpret_cast<float4*>(&b8[0]) = *reinterpret_cast<const float4*>(bjp);
            *reinterpret_cast<float4*>(&b8[4]) = *reinterpret_cast<const float4*>(bjp + 4);
            bf16x8 bhi, blo;
            split_bf16(b8, bhi, blo);
            acc[j] = __builtin_amdgcn_mfma_f32_16x16x32_bf16(ahi, bhi, acc[j], 0, 0, 0);
            acc[j] = __builtin_amdgcn_mfma_f32_16x16x32_bf16(ahi, blo, acc[j], 0, 0, 0);
            acc[j] = __builtin_amdgcn_mfma_f32_16x16x32_bf16(alo, bhi, acc[j], 0, 0, 0);
        }
    }

    __shared__ f32x4 red[4][4][64];   // partials from kh==1 waves (16 KB)
    if (kh == 1) {
        #pragma unroll
        for (int j = 0; j < 4; ++j) red[wm][j][l] = acc[j];
    }
    __syncthreads();
    if (kh == 0) {
        float p[4] = {0.f, 0.f, 0.f, 0.f};
        #pragma unroll
        for (int j = 0; j < 4; ++j) {
            f32x4 s = acc[j] + red[wm][j][l];
            int n = n0 + j * 16 + row;
            float bb = bias ? bias[n] : 0.f;
            float bkv = CVEC ? bk[n] : 0.f;
            #pragma unroll
            for (int r = 0; r < 4; ++r) {
                int m = m0 + wm * 16 + kg * 4 + r;
                float o = s[r] * scale + bb;
                C[(size_t)m * H + n] = o;
                if (CVEC) p[r] += o * bkv;
            }
        }
        if (CVEC) {
            #pragma unroll
            for (int r = 0; r < 4; ++r) {
                #pragma unroll
                for (int off = 1; off < 16; off <<= 1)
                    p[r] += __shfl_xor(p[r], off);
            }
            if (row == 0) {
                #pragma unroll
                for (int r = 0; r < 4; ++r)
                    atomicAdd(&cvec[m0 + wm * 16 + kg * 4 + r], p[r] * cscale);
            }
        }
    }
}

// ---------------------------------------------------------------------------
// N-proj, B read strided directly from Wk[k][n]: N = (q @ Wk) * scale
// -> pre-split bf16 hi/lo [m][n]. 512-thr split-K(x2).
// ---------------------------------------------------------------------------
__global__ __launch_bounds__(512)
void ngemm_direct(const float* __restrict__ A, const float* __restrict__ Wk,
                  __bf16* __restrict__ Nhi, __bf16* __restrict__ Nlo, float scale)
{
    const int m0 = blockIdx.x * 64;
    const int n0 = blockIdx.y * 64;
    const int t   = threadIdx.x;
    const int w   = t >> 6;
    const int wm  = w & 3;
    const int kh  = w >> 2;
    const int l   = t & 63;
    const int row = l & 15;
    const int kg  = l >> 4;

    const float* ap = A + (size_t)(m0 + wm * 16 + row) * H + kh * 512 + kg * 8;
    const float* bp = Wk + (size_t)(kh * 512 + kg * 8) * H + n0 + row;

    f32x4 acc[4] = {};
    for (int k0 = 0; k0 < 512; k0 += 32) {
        float a8[8];
        *reinterpret_cast<float4*>(&a8[0]) = *reinterpret_cast<const float4*>(ap + k0);
        *reinterpret_cast<float4*>(&a8[4]) = *reinterpret_cast<const float4*>(ap + k0 + 4);
        bf16x8 ahi, alo;
        split_bf16(a8, ahi, alo);
        #pragma unroll
        for (int j = 0; j < 4; ++j) {
            float b8[8];
            #pragma unroll
            for (int e = 0; e < 8; ++e)
                b8[e] = bp[(size_t)(k0 + e) * H + j * 16];
            bf16x8 bhi, blo;
            split_bf16(b8, bhi, blo);
            acc[j] = __builtin_amdgcn_mfma_f32_16x16x32_bf16(ahi, bhi, acc[j], 0, 0, 0);
            acc[j] = __builtin_amdgcn_mfma_f32_16x16x32_bf16(ahi, blo, acc[j], 0, 0, 0);
            acc[j] = __builtin_amdgcn_mfma_f32_16x16x32_bf16(alo, bhi, acc[j], 0, 0, 0);
        }
    }

    __shared__ f32x4 red[4][4][64];
    if (kh == 1) {
        #pragma unroll
        for (int j = 0; j < 4; ++j) red[wm][j][l] = acc[j];
    }
    __syncthreads();
    if (kh == 0) {
        #pragma unroll
        for (int j = 0; j < 4; ++j) {
            f32x4 s = acc[j] + red[wm][j][l];
            int n = n0 + j * 16 + row;
            #pragma unroll
            for (int r = 0; r < 4; ++r) {
                int m = m0 + wm * 16 + kg * 4 + r;
                float v = s[r] * scale;
                __bf16 hi = (__bf16)v;
                Nhi[(size_t)m * H + n] = hi;
                Nlo[(size_t)m * H + n] = (__bf16)(v - (float)hi);
            }
        }
    }
}

// ---------------------------------------------------------------------------
// scores[b,s,qi] = sum_h keys[b,s,h]*N[b,qi,h] + c[b,qi]
// R17-template pipeline: ALL operands staged via global_load_lds, 3-buffer,
// staged 2 chunks ahead, counted vmcnt + raw s_barrier, setprio on MFMA.
// 32-k chunks x 32. Keys [128s][4slot][8]f32 src-swizzled slot=kb^(s&3);
// N hi/lo [64qi][4slot][8]bf16 (waves 0-3 hi, 4-7 lo). Fused softmax stats.
// ---------------------------------------------------------------------------
__global__ __launch_bounds__(512, 2)
void scores_mfma(const float* __restrict__ keys,
                 const __bf16* __restrict__ Nhi, const __bf16* __restrict__ Nlo,
                 const float* __restrict__ cvec, float* __restrict__ scores,
                 float* __restrict__ pmax, float* __restrict__ psum)
{
    const int id = blockIdx.x;          // 512 blocks
    const int x  = id & 7;
    const int m  = id >> 3;             // 0..63
    const int b  = 2 * x + (m >> 5);    // 2 batches per XCD
    const int ch = m & 31;
    const int s0 = ch * 128;

    const int t   = threadIdx.x;
    const int w   = t >> 6;             // 0..7
    const int l   = t & 63;
    const int row = l & 15;
    const int kg  = l >> 4;

    __shared__ float  klds[3][128][4][8];   // 48 KB
    __shared__ __bf16 nhlds[3][64][4][8];   // 12 KB
    __shared__ __bf16 nllds[3][64][4][8];   // 12 KB
    __shared__ float  redm[8][64];          // 2 KB

    const float*  kbase = keys + ((size_t)b * SEQ + s0) * H;
    const __bf16* nhb   = Nhi + (size_t)b * BQ * H;
    const __bf16* nlb   = Nlo + (size_t)b * BQ * H;

    // keys: 2 gloads/thread (4096 f32 / 512 thr = 8 f32)
    #define KSTAGE(buf, c)                                                     \
        {                                                                      \
            _Pragma("unroll")                                                  \
            for (int ii = 0; ii < 2; ++ii) {                                   \
                int d  = w * 512 + ii * 256 + l * 4;                           \
                int ss = d >> 5;                                               \
                int sb = (d >> 3) & 3;                                         \
                int e0 = d & 7;                                                \
                const float* src = kbase + (size_t)ss * H + (c) * 32 +         \
                                   ((sb ^ (ss & 3)) << 3) + e0;                \
                gload_lds16(src, (void*)(&klds[buf][0][0][0] + w * 512 + ii * 256)); \
            }                                                                  \
        }
    // N: 1 gload/thread; waves 0-3 stage hi, waves 4-7 stage lo
    #define NSTAGE(buf, c)                                                     \
        {                                                                      \
            int d   = (w & 3) * 512 + l * 8;                                   \
            int qi_ = d >> 5;                                                  \
            int nb_ = (d >> 3) & 3;                                            \
            const __bf16* srcN = ((w < 4) ? nhb : nlb) + (size_t)qi_ * H +     \
                                 (c) * 32 + ((nb_ ^ (qi_ & 3)) << 3);          \
            __bf16* dstN = ((w < 4) ? &nhlds[buf][0][0][0]                     \
                                    : &nllds[buf][0][0][0]) + (w & 3) * 512;   \
            gload_lds16(srcN, (void*)dstN);                                    \
        }

    f32x4 acc[4] = {};
    KSTAGE(0, 0); NSTAGE(0, 0);
    KSTAGE(1, 1); NSTAGE(1, 1);

    const int sw    = w * 16 + row;       // this lane's s row in block
    const int aslot = kg ^ (row & 3);     // (sw&3)==(row&3); (qi&3)==(row&3)

    for (int ks = 0; ks < 32; ++ks) {
        const int buf = ks % 3;
        // issue stage ks+2, then wait so stage ks is fully landed (3/stage)
        if (ks + 2 < 32) {
            const int nb2 = (ks + 2) % 3;
            KSTAGE(nb2, ks + 2); NSTAGE(nb2, ks + 2);
            asm volatile("s_waitcnt vmcnt(6)" ::: "memory");
        } else if (ks + 1 < 32) {
            asm volatile("s_waitcnt vmcnt(3)" ::: "memory");
        } else {
            asm volatile("s_waitcnt vmcnt(0)" ::: "memory");
        }
        __builtin_amdgcn_sched_barrier(0);
        __builtin_amdgcn_s_barrier();      // chunk ks visible to all waves
        __builtin_amdgcn_sched_barrier(0);

        __builtin_amdgcn_s_setprio(1);
        float a8[8];
        *reinterpret_cast<float4*>(&a8[0]) =
            *reinterpret_cast<const float4*>(&klds[buf][sw][aslot][0]);
        *reinterpret_cast<float4*>(&a8[4]) =
            *reinterpret_cast<const float4*>(&klds[buf][sw][aslot][4]);
        bf16x8 ahi, alo;
        split_bf16(a8, ahi, alo);
        #pragma unroll
        for (int j = 0; j < 4; ++j) {
            const int qi = j * 16 + row;
            bf16x8 bhi = *reinterpret_cast<const bf16x8*>(&nhlds[buf][qi][aslot][0]);
            bf16x8 blo = *reinterpret_cast<const bf16x8*>(&nllds[buf][qi][aslot][0]);
            acc[j] = __builtin_amdgcn_mfma_f32_16x16x32_bf16(ahi, bhi, acc[j], 0, 0, 0);
            acc[j] = __builtin_amdgcn_mfma_f32_16x16x32_bf16(ahi, blo, acc[j], 0, 0, 0);
            acc[j] = __builtin_amdgcn_mfma_f32_16x16x32_bf16(alo, bhi, acc[j], 0, 0, 0);
        }
        __builtin_amdgcn_s_setprio(0);
        __builtin_amdgcn_sched_barrier(0);
        __builtin_amdgcn_s_barrier();      // compute(ks) done everywhere
        __builtin_amdgcn_sched_barrier(0);
    }
    #undef KSTAGE
    #undef NSTAGE

    // epilogue: add cvec, write scores
    #pragma unroll
    for (int j = 0; j < 4; ++j) {
        int qi = j * 16 + row;
        float cv = cvec[b * BQ + qi];
        #pragma unroll
        for (int r = 0; r < 4; ++r) {
            acc[j][r] += cv;
            int s = s0 + w * 16 + kg * 4 + r;
            scores[((size_t)b * SEQ + s) * BQ + qi] = acc[j][r];
        }
    }
    // fused partial stats over this block's 128 s-rows
    float mj[4];
    #pragma unroll
    for (int j = 0; j < 4; ++j) {
        float mm = fmaxf(fmaxf(acc[j][0], acc[j][1]), fmaxf(acc[j][2], acc[j][3]));
        mm = fmaxf(mm, __shfl_xor(mm, 16));
        mm = fmaxf(mm, __shfl_xor(mm, 32));
        mj[j] = mm;
    }
    __syncthreads();
    if (kg == 0) {
        #pragma unroll
        for (int j = 0; j < 4; ++j) redm[w][j * 16 + row] = mj[j];
    }
    __syncthreads();
    float Mj[4];
    #pragma unroll
    for (int j = 0; j < 4; ++j) {
        const int qi = j * 16 + row;
        float M = redm[0][qi];
        #pragma unroll
        for (int ww = 1; ww < 8; ++ww) M = fmaxf(M, redm[ww][qi]);
        Mj[j] = M;
    }
    float sj[4];
    #pragma unroll
    for (int j = 0; j < 4; ++j) {
        float s = 0.f;
        #pragma unroll
        for (int r = 0; r < 4; ++r) s += __expf(acc[j][r] - Mj[j]);
        s += __shfl_xor(s, 16);
        s += __shfl_xor(s, 32);
        sj[j] = s;
    }
    __syncthreads();
    if (kg == 0) {
        #pragma unroll
        for (int j = 0; j < 4; ++j) redm[w][j * 16 + row] = sj[j];
    }
    __syncthreads();
    if (w == 0 && kg == 0) {
        #pragma unroll
        for (int j = 0; j < 4; ++j) {
            const int qi = j * 16 + row;
            float ss = 0.f;
            #pragma unroll
            for (int ww = 0; ww < 8; ++ww) ss += redm[ww][qi];
            pmax[((size_t)b * 32 + ch) * 64 + qi] = Mj[j];
            psum[((size_t)b * 32 + ch) * 64 + qi] = ss;
        }
    }
}

// ---------------------------------------------------------------------------
// normalize in place (inline global-stat combine) + bf16 transposed copy
// ---------------------------------------------------------------------------
__global__ __launch_bounds__(256)
void sm_norm(float* __restrict__ attn, const float* __restrict__ pmax,
             const float* __restrict__ psum, __hip_bfloat16* __restrict__ abfT)
{
    __shared__ float tile[64][133];
    const int b  = blockIdx.y;
    const int ch = blockIdx.x;
    const int t  = threadIdx.x;
    const int qi = t & 63;
    const int g  = t >> 6;

    float M = -1e30f;
    #pragma unroll 4
    for (int c = 0; c < 32; ++c)
        M = fmaxf(M, pmax[((size_t)b * 32 + c) * 64 + qi]);
    float ssum = 0.f;
    #pragma unroll 4
    for (int c = 0; c < 32; ++c)
        ssum += psum[((size_t)b * 32 + c) * 64 + qi] *
                __expf(pmax[((size_t)b * 32 + c) * 64 + qi] - M);
    const float inv = 1.f / ssum;

    float* sb = attn + ((size_t)b * SEQ + ch * 128) * BQ;
    #pragma unroll 8
    for (int i = 0; i < 32; ++i) {
        int sl = g + i * 4;
        size_t idx = (size_t)sl * BQ + qi;
        float w = __expf(sb[idx] - M) * inv;
        sb[idx] = w;
        tile[qi][sl] = w;
    }
    __syncthreads();
    const int qo = t >> 2;
    const int c  = (t & 3) * 32;
    __hip_bfloat16* dst = abfT + ((size_t)(b * BQ + qo)) * SEQ + ch * 128 + c;
    #pragma unroll
    for (int v = 0; v < 4; ++v) {
        bf16x8 w8;
        #pragma unroll
        for (int e = 0; e < 8; ++e)
            w8[e] = (__bf16)tile[qo][c + v * 8 + e];
        *reinterpret_cast<bf16x8*>(dst + v * 8) = w8;
    }
}

// ---------------------------------------------------------------------------
// Tpart[sc][b][qi][h] = sum_{s in chunk} abfT[b,qi,s] * values[b,s,h]
// R17 pipeline: gload_lds 3-buffer, counted vmcnt, raw barriers, setprio.
// ---------------------------------------------------------------------------
template<int SC>
__global__ __launch_bounds__(256)
void tmat_mfma(const __hip_bfloat16* __restrict__ abfT,
               const float* __restrict__ values,
               float* __restrict__ Tpart)
{
    constexpr int schunk = SEQ / SC;
    constexpr int nk = schunk / 32;

    const int i  = blockIdx.x;
    const int h0 = ((i >> 3) & 7) * 128;
    const int g  = (i & 7) + 8 * (i >> 6);
    const int b  = g / SC;
    const int sc = g % SC;

    const int w   = threadIdx.x >> 6;
    const int l   = threadIdx.x & 63;
    const int row = l & 15;
    const int kg  = l >> 4;
    const int sbase = sc * schunk;

    __shared__ float vlds[3][32][128];            // 48 KB
    __shared__ __hip_bfloat16 alds[3][64][32];    // 12 KB

    const __hip_bfloat16* ab = abfT + (size_t)b * BQ * SEQ + sbase;
    const float* vb = values + ((size_t)b * SEQ + sbase) * H + h0;

    #define VSTAGE(buf, c)                                                     \
        {                                                                      \
            _Pragma("unroll")                                                  \
            for (int ii = 0; ii < 4; ++ii) {                                   \
                int elem = w * 1024 + ii * 256 + l * 4;                        \
                int k    = elem >> 7;                                          \
                int cc   = elem & 127;                                         \
                int csw  = cc ^ ((k >> 3) << 4);                               \
                const float* src = vb + (size_t)((c) * 32 + k) * H + csw;      \
                gload_lds16(src, (void*)(&vlds[buf][0][0] + w * 1024 + ii * 256)); \
            }                                                                  \
        }
    #define ASTAGE(buf, c)                                                     \
        {                                                                      \
            int aqi = w * 16 + (l >> 2);                                       \
            const __hip_bfloat16* srcA =                                       \
                ab + (size_t)aqi * SEQ + (c) * 32 + (l & 3) * 8;               \
            gload_lds16(srcA, (void*)(&alds[buf][0][0] + w * 512));            \
        }

    f32x4 acc[4][2] = {};
    ASTAGE(0, 0); VSTAGE(0, 0);
    ASTAGE(1, 1); VSTAGE(1, 1);

    for (int ks = 0; ks < nk; ++ks) {
        const int buf = ks % 3;
        if (ks + 2 < nk) {
            const int nb2 = (ks + 2) % 3;
            ASTAGE(nb2, ks + 2); VSTAGE(nb2, ks + 2);
            asm volatile("s_waitcnt vmcnt(10)" ::: "memory");
        } else if (ks + 1 < nk) {
            asm volatile("s_waitcnt vmcnt(5)" ::: "memory");
        } else {
            asm volatile("s_waitcnt vmcnt(0)" ::: "memory");
        }
        __builtin_amdgcn_sched_barrier(0);
        __builtin_amdgcn_s_barrier();
        __builtin_amdgcn_sched_barrier(0);

        __builtin_amdgcn_s_setprio(1);
        bf16x8 a[4];
        #pragma unroll
        for (int q = 0; q < 4; ++q)
            a[q] = *reinterpret_cast<const bf16x8*>(&alds[buf][q * 16 + row][kg * 8]);
        #pragma unroll
        for (int j = 0; j < 2; ++j) {
            const int col = (w * 32 + j * 16 + row) ^ (kg << 4);
            float b8[8];
            #pragma unroll
            for (int e = 0; e < 8; ++e)
                b8[e] = vlds[buf][kg * 8 + e][col];
            bf16x8 bhi, blo;
            split_bf16(b8, bhi, blo);
            #pragma unroll
            for (int q = 0; q < 4; ++q) {
                acc[q][j] = __builtin_amdgcn_mfma_f32_16x16x32_bf16(a[q], bhi, acc[q][j], 0, 0, 0);
                acc[q][j] = __builtin_amdgcn_mfma_f32_16x16x32_bf16(a[q], blo, acc[q][j], 0, 0, 0);
            }
        }
        __builtin_amdgcn_s_setprio(0);
        __builtin_amdgcn_sched_barrier(0);
        __builtin_amdgcn_s_barrier();
        __builtin_amdgcn_sched_barrier(0);
    }
    #undef VSTAGE
    #undef ASTAGE

    float* tp = Tpart + ((size_t)sc * NB + b) * BQ * H;
    #pragma unroll
    for (int q = 0; q < 4; ++q) {
        #pragma unroll
        for (int j = 0; j < 2; ++j) {
            int h = h0 + w * 32 + j * 16 + row;
            #pragma unroll
            for (int r = 0; r < 4; ++r) {
                int qi = q * 16 + kg * 4 + r;
                tp[(size_t)qi * H + h] = acc[q][j][r];
            }
        }
    }
}

// ---------------------------------------------------------------------------
// In-place partial reduction: Tpart[0][i] = sum_p Tpart[p][i]
// ---------------------------------------------------------------------------
template<int SC>
__global__ __launch_bounds__(256)
void tsum_kernel(float* __restrict__ Tpart)
{
    const size_t stride = (size_t)NB * BQ * H;
    size_t i = ((size_t)blockIdx.x * 256 + threadIdx.x) * 4;
    f32x4 s = *reinterpret_cast<const f32x4*>(Tpart + i);
    #pragma unroll
    for (int p = 1; p < SC; ++p)
        s += *reinterpret_cast<const f32x4*>(Tpart + p * stride + i);
    *reinterpret_cast<f32x4*>(Tpart + i) = s;
}

// ---------------------------------------------------------------------------
extern "C" void kernel_launch(void* const* d_in, const int* in_sizes, int n_in,
                              void* d_out, int out_size, void* d_ws, size_t ws_size,
                              hipStream_t stream)
{
    const float* queries = (const float*)d_in[0];
    const float* keys    = (const float*)d_in[1];
    const float* values  = (const float*)d_in[2];
    const float* Wq = (const float*)d_in[3];
    const float* bq = (const float*)d_in[4];
    const float* Wk = (const float*)d_in[5];
    const float* bk = (const float*)d_in[6];
    const float* Wv = (const float*)d_in[7];
    const float* bv = (const float*)d_in[8];

    float* out     = (float*)d_out;
    float* context = out;                          // 16*64*1024 f32
    float* attn    = out + (size_t)NB * BQ * H;    // 16*4096*64 f32

    const int SC = (ws_size >= (41ull << 20)) ? 8 : 2;

    char* ws = (char*)d_ws;
    float* q     = (float*)ws;                              // 4 MB  [0,4)
    __bf16* Nhi  = (__bf16*)(ws + (8ull << 20));            // 2 MB  [8,10)
    __bf16* Nlo  = (__bf16*)(ws + (10ull << 20));           // 2 MB  [10,12)
    float* Tpart = (float*)ws;                              // SC*4 MB (overlaps q/N, dead by tmat)
    __hip_bfloat16* abfT = (__hip_bfloat16*)(ws + (size_t)SC * (4ull << 20)); // 8 MB
    char* smalls = ws + (size_t)SC * (4ull << 20) + (8ull << 20);
    float* cvec  = (float*)smalls;                          // 4 KB
    float* pmax  = (float*)(smalls + (128u << 10));         // 128 KB
    float* psum  = (float*)(smalls + (512u << 10));         // 128 KB

    const float scale = 0.03125f; // 1/sqrt(1024)

    // cvec accumulated atomically in q-GEMM epilogue
    hipMemsetAsync(cvec, 0, (size_t)NB * BQ * sizeof(float), stream);
    // q = queries @ Wq^T + bq  (+ cvec = scale*(q . bk))
    gemm_bt_512<true><<<dim3(16, 16), 512, 0, stream>>>(
        queries, Wq, bq, q, 1.0f, bk, cvec, scale);
    // N = (q @ Wk) * scale -> pre-split bf16 hi/lo
    ngemm_direct<<<dim3(16, 16), 512, 0, stream>>>(q, Wk, Nhi, Nlo, scale);
    // scores + fused per-chunk softmax stats (gload_lds 3-buffer pipeline)
    scores_mfma<<<512, 512, 0, stream>>>(keys, Nhi, Nlo, cvec, attn, pmax, psum);
    // normalize (inline stat combine) + bf16 transposed copy
    sm_norm<<<dim3(32, NB), 256, 0, stream>>>(attn, pmax, psum, abfT);
    // T partials = attn^T @ values
    if (SC == 8) tmat_mfma<8><<<8 * NB * 8, 256, 0, stream>>>(abfT, values, Tpart);
    else         tmat_mfma<2><<<8 * NB * 2, 256, 0, stream>>>(abfT, values, Tpart);
    // Tsum (in place into partial 0)
    if (SC == 8) tsum_kernel<8><<<1024, 256, 0, stream>>>(Tpart);
    else         tsum_kernel<2><<<1024, 256, 0, stream>>>(Tpart);
    // context = Tsum @ Wv^T + bv
    gemm_bt_512<false><<<dim3(16, 16), 512, 0, stream>>>(
        Tpart, Wv, bv, context, 1.0f, nullptr, nullptr, 0.f);
}